// Round 1
// baseline (591.381 us; speedup 1.0000x reference)
//
#include <hip/hip_runtime.h>

// ---------------------------------------------------------------------------
// Problem: AttentionActPrune — full MHA forward.
// B=4, S=2048, H=16, DH=64, D=1024. All fp32 in/out; threshold is 2% of
// max|ref| (6.4e-3) so bf16 MFMA compute is safe.
// Pipeline: cvt(X,W*) -> 3x GEMM (Q,K,V bf16) -> flash-attn -> GEMM (out fp32)
// ---------------------------------------------------------------------------

typedef __bf16 bf16;
typedef __bf16 bf16x8 __attribute__((ext_vector_type(8)));
typedef __bf16 bf16x4 __attribute__((ext_vector_type(4)));
typedef float  floatx4 __attribute__((ext_vector_type(4)));

#define NB   4
#define SEQ  2048
#define NH   16
#define DH   64
#define DIM  1024
#define MTOT (NB * SEQ)   // 8192

__device__ __forceinline__ floatx4 zero4() {
    floatx4 z; z[0] = 0.f; z[1] = 0.f; z[2] = 0.f; z[3] = 0.f; return z;
}

// async global->LDS, 16B per lane. LDS dest = wave-uniform base + lane*16.
__device__ __forceinline__ void load_lds16(const bf16* g, bf16* l) {
    __builtin_amdgcn_global_load_lds(
        (__attribute__((address_space(1))) void*)g,
        (__attribute__((address_space(3))) void*)l,
        16, 0, 0);
}

// ---------------------------------------------------------------------------
// fp32 -> bf16 conversion (vectorized 4/thread)
// ---------------------------------------------------------------------------
__global__ __launch_bounds__(256) void cvt_kernel(const float* __restrict__ in,
                                                  bf16* __restrict__ out, int n) {
    int i = (blockIdx.x * 256 + threadIdx.x) * 4;
    if (i + 3 < n) {
        float4 f = *(const float4*)(in + i);
        bf16x4 o;
        o[0] = (bf16)f.x; o[1] = (bf16)f.y; o[2] = (bf16)f.z; o[3] = (bf16)f.w;
        *(bf16x4*)(out + i) = o;
    }
}

// ---------------------------------------------------------------------------
// GEMM: C[m][n] = sum_k A[m][k] * W[n][k] + bias[n]
// A: [M][K] bf16 row-major, W: [N][K] bf16 row-major (torch Linear weight),
// C: [M][N] OutT. 128x128 tile, BK=32, 4 waves (2x2), 4x4 MFMA tiles/wave.
// m97 structure: global_load_lds width-16 staging.
// ---------------------------------------------------------------------------
template <typename OutT>
__global__ __launch_bounds__(256) void gemm_bt(const bf16* __restrict__ A,
                                               const bf16* __restrict__ W,
                                               const float* __restrict__ bias,
                                               OutT* __restrict__ C,
                                               int M, int N, int K) {
    __shared__ __align__(16) bf16 As[128 * 32];
    __shared__ __align__(16) bf16 Bs[128 * 32];

    const int tid  = threadIdx.x;
    const int wave = tid >> 6, lane = tid & 63;
    const int quad = lane >> 4, l16 = lane & 15;
    const int m0 = blockIdx.y * 128, n0 = blockIdx.x * 128;
    const int wm = (wave & 1) * 64, wn = (wave >> 1) * 64;

    floatx4 acc[4][4];
#pragma unroll
    for (int mi = 0; mi < 4; mi++)
#pragma unroll
        for (int ni = 0; ni < 4; ni++) acc[mi][ni] = zero4();

    for (int k0 = 0; k0 < K; k0 += 32) {
        __syncthreads();  // prev-iter LDS reads complete before overwrite
#pragma unroll
        for (int i = 0; i < 2; i++) {
            const int cb = wave * 128 + i * 64;   // wave-uniform chunk base
            const int c  = cb + lane;             // this lane's 16B chunk
            const int row = c >> 2;               // 0..127
            const int kc  = (c & 3) * 8;          // 0,8,16,24
            load_lds16(A + (size_t)(m0 + row) * K + k0 + kc, &As[cb * 8]);
            load_lds16(W + (size_t)(n0 + row) * K + k0 + kc, &Bs[cb * 8]);
        }
        __syncthreads();  // drains vmcnt(0): staging visible

        bf16x8 af[4], bfr[4];
#pragma unroll
        for (int mi = 0; mi < 4; mi++)
            af[mi] = *(const bf16x8*)&As[(wm + mi * 16 + l16) * 32 + quad * 8];
#pragma unroll
        for (int ni = 0; ni < 4; ni++)
            bfr[ni] = *(const bf16x8*)&Bs[(wn + ni * 16 + l16) * 32 + quad * 8];
#pragma unroll
        for (int mi = 0; mi < 4; mi++)
#pragma unroll
            for (int ni = 0; ni < 4; ni++)
                acc[mi][ni] = __builtin_amdgcn_mfma_f32_16x16x32_bf16(
                    af[mi], bfr[ni], acc[mi][ni], 0, 0, 0);
    }

    // epilogue: C/D layout col=lane&15, row=quad*4+reg
#pragma unroll
    for (int mi = 0; mi < 4; mi++) {
        const int rbase = m0 + wm + mi * 16 + quad * 4;
#pragma unroll
        for (int ni = 0; ni < 4; ni++) {
            const int col = n0 + wn + ni * 16 + l16;
            const float bval = bias[col];
#pragma unroll
            for (int i = 0; i < 4; i++)
                C[(size_t)(rbase + i) * N + col] = (OutT)(acc[mi][ni][i] + bval);
        }
    }
}

// ---------------------------------------------------------------------------
// Flash attention, one wave = 16 Q rows of one (b,h). KV tiles of 32.
// Q,K,V,Ctx layout: [B,S,H*DH] bf16 (merged heads, GEMM-natural).
// ---------------------------------------------------------------------------
__global__ __launch_bounds__(256) void attn_kernel(const bf16* __restrict__ Q,
                                                   const bf16* __restrict__ K,
                                                   const bf16* __restrict__ V,
                                                   bf16* __restrict__ Ctx) {
    __shared__ __align__(16) bf16 p_lds[4][16][32];  // per-wave P transpose buf

    const int tid  = threadIdx.x;
    const int wave = tid >> 6, lane = tid & 63;
    const int quad = lane >> 4, l16 = lane & 15;
    const int gw = blockIdx.x * 4 + wave;   // 0..8191
    const int qt = gw & 127;                // q-tile (16 rows each)
    const int h  = (gw >> 7) & 15;
    const int b  = gw >> 11;

    const size_t base_bh = (size_t)b * SEQ * DIM + (size_t)h * DH;

    // Q A-fragments: A[m=l16][k=quad*8+j], two K=32 halves of DH=64
    const bf16* qp = Q + base_bh + (size_t)(qt * 16 + l16) * DIM + quad * 8;
    const bf16x8 a0 = *(const bf16x8*)qp;
    const bf16x8 a1 = *(const bf16x8*)(qp + 32);

    floatx4 acc[4];
#pragma unroll
    for (int dt = 0; dt < 4; dt++) acc[dt] = zero4();
    float m_i[4], l_i[4];
#pragma unroll
    for (int i = 0; i < 4; i++) { m_i[i] = -__builtin_inff(); l_i[i] = 0.f; }

    for (int kv0 = 0; kv0 < SEQ; kv0 += 32) {
        // --- scores: S[row=quad*4+i][col=t*16+l16] ---
        floatx4 s[2];
#pragma unroll
        for (int t = 0; t < 2; t++) {
            const bf16* kp = K + base_bh + (size_t)(kv0 + t * 16 + l16) * DIM + quad * 8;
            bf16x8 kb0 = *(const bf16x8*)kp;
            bf16x8 kb1 = *(const bf16x8*)(kp + 32);
            floatx4 z = zero4();
            z = __builtin_amdgcn_mfma_f32_16x16x32_bf16(a0, kb0, z, 0, 0, 0);
            z = __builtin_amdgcn_mfma_f32_16x16x32_bf16(a1, kb1, z, 0, 0, 0);
#pragma unroll
            for (int i = 0; i < 4; i++) s[t][i] = z[i] * 0.125f;  // 1/sqrt(64)
        }

        // --- online softmax per row (reduce over 16 lanes of the quad) ---
        float p0[4], p1[4], alpha[4];
#pragma unroll
        for (int i = 0; i < 4; i++) {
            float mx = fmaxf(s[0][i], s[1][i]);
#pragma unroll
            for (int off = 8; off >= 1; off >>= 1)
                mx = fmaxf(mx, __shfl_xor(mx, off));
            const float mnew = fmaxf(m_i[i], mx);
            alpha[i] = __expf(m_i[i] - mnew);
            m_i[i] = mnew;
            p0[i] = __expf(s[0][i] - mnew);
            p1[i] = __expf(s[1][i] - mnew);
            float rs = p0[i] + p1[i];
#pragma unroll
            for (int off = 8; off >= 1; off >>= 1)
                rs += __shfl_xor(rs, off);
            l_i[i] = l_i[i] * alpha[i] + rs;
        }

        // --- P: C-layout -> A-layout via per-wave LDS round-trip ---
#pragma unroll
        for (int i = 0; i < 4; i++) {
            p_lds[wave][quad * 4 + i][l16]      = (bf16)p0[i];
            p_lds[wave][quad * 4 + i][16 + l16] = (bf16)p1[i];
        }
        const bf16x8 pa = *(const bf16x8*)&p_lds[wave][l16][quad * 8];

        // --- V B-fragments: B[k=quad*8+jj][n=dt*16+l16] = V[kv0+k][dt*16+n]
        bf16x8 vb[4];
        const bf16* vbase = V + base_bh + (size_t)(kv0 + quad * 8) * DIM + l16;
#pragma unroll
        for (int jj = 0; jj < 8; jj++) {
            const bf16* vr = vbase + (size_t)jj * DIM;
#pragma unroll
            for (int dt = 0; dt < 4; dt++) vb[dt][jj] = vr[dt * 16];
        }

        // --- rescale + PV ---
#pragma unroll
        for (int dt = 0; dt < 4; dt++)
#pragma unroll
            for (int i = 0; i < 4; i++) acc[dt][i] *= alpha[i];
#pragma unroll
        for (int dt = 0; dt < 4; dt++)
            acc[dt] = __builtin_amdgcn_mfma_f32_16x16x32_bf16(pa, vb[dt], acc[dt], 0, 0, 0);
    }

    // --- normalize + store ctx (merged-head layout) ---
    float inv[4];
#pragma unroll
    for (int i = 0; i < 4; i++) inv[i] = 1.0f / l_i[i];
    bf16* cp = Ctx + base_bh + (size_t)(qt * 16 + quad * 4) * DIM + l16;
#pragma unroll
    for (int i = 0; i < 4; i++)
#pragma unroll
        for (int dt = 0; dt < 4; dt++)
            cp[(size_t)i * DIM + dt * 16] = (bf16)(acc[dt][i] * inv[i]);
}

// ---------------------------------------------------------------------------
extern "C" void kernel_launch(void* const* d_in, const int* in_sizes, int n_in,
                              void* d_out, int out_size, void* d_ws, size_t ws_size,
                              hipStream_t stream) {
    const float* X  = (const float*)d_in[0];
    const float* Wq = (const float*)d_in[1];
    const float* bq = (const float*)d_in[2];
    const float* Wk = (const float*)d_in[3];
    const float* bk = (const float*)d_in[4];
    const float* Wv = (const float*)d_in[5];
    const float* bv = (const float*)d_in[6];
    const float* Wo = (const float*)d_in[7];
    const float* bo = (const float*)d_in[8];
    float* out = (float*)d_out;

    const size_t MD = (size_t)MTOT * DIM;  // 8,388,608
    const size_t DD = (size_t)DIM * DIM;   // 1,048,576

    bf16* Xb  = (bf16*)d_ws;   // X bf16; reused as ctx after QKV GEMMs
    bf16* Qb  = Xb + MD;
    bf16* Kb  = Qb + MD;
    bf16* Vb  = Kb + MD;
    bf16* Wqb = Vb + MD;
    bf16* Wkb = Wqb + DD;
    bf16* Wvb = Wkb + DD;
    bf16* Wob = Wvb + DD;
    if (ws_size < (MD * 4 + DD * 4) * sizeof(bf16)) return;  // need ~72 MiB

    // converts
    cvt_kernel<<<(int)(MD / 4 / 256), 256, 0, stream>>>(X, Xb, (int)MD);
    cvt_kernel<<<(int)(DD / 4 / 256), 256, 0, stream>>>(Wq, Wqb, (int)DD);
    cvt_kernel<<<(int)(DD / 4 / 256), 256, 0, stream>>>(Wk, Wkb, (int)DD);
    cvt_kernel<<<(int)(DD / 4 / 256), 256, 0, stream>>>(Wv, Wvb, (int)DD);
    cvt_kernel<<<(int)(DD / 4 / 256), 256, 0, stream>>>(Wo, Wob, (int)DD);

    // QKV projections
    dim3 gg(DIM / 128, MTOT / 128);  // (8, 64)
    gemm_bt<bf16><<<gg, 256, 0, stream>>>(Xb, Wqb, bq, Qb, MTOT, DIM, DIM);
    gemm_bt<bf16><<<gg, 256, 0, stream>>>(Xb, Wkb, bk, Kb, MTOT, DIM, DIM);
    gemm_bt<bf16><<<gg, 256, 0, stream>>>(Xb, Wvb, bv, Vb, MTOT, DIM, DIM);

    // flash attention: 8192 waves = 2048 blocks x 4 waves; ctx -> Xb (aliased)
    attn_kernel<<<NB * NH * (SEQ / 16) / 4, 256, 0, stream>>>(Qb, Kb, Vb, Xb);

    // output projection (fp32 out + bias)
    gemm_bt<float><<<gg, 256, 0, stream>>>(Xb, Wob, bo, out, MTOT, DIM, DIM);
}